// Round 19
// baseline (55.090 us; speedup 1.0000x reference)
//
#include <hip/hip_runtime.h>
#include <math.h>

#define BB 16
#define NN 4096
#define EE 65536
#define IN_F 128
#define HH 512
#define D1 512
#define D2 32768
#define EPSV 1e-5f
#define CAP 64  // fixed CSR row capacity; dst ~ Binomial(65536,1/4096), P(deg>64)~1e-19

// ---------------- stage A: GRU (0..127) || csr2 sentinel (128..1151) || cursor zero (1152..1168)
//                  || sm precompute (1169) || pv build (1170..2194) ----------------
// pv[n][l] = raw pos (l = b*4+c, c<3); dis applied per-edge in gath1.
// sm layout: [0..8] W0M3 (3x3 row-major k*3+c), [9..11] b0@M3, [12..14] b1@Wh

__global__ __launch_bounds__(256) void k_stageA(
        int* __restrict__ csr2, int* __restrict__ cursor,
        const float* __restrict__ W0, const float* __restrict__ b0,
        const float* __restrict__ W1, const float* __restrict__ b1,
        const float* __restrict__ w_out, float* __restrict__ sm,
        const float* __restrict__ pos, float* __restrict__ pv,
        const float* __restrict__ x, const float* __restrict__ hidden,
        const float* __restrict__ w_ih, const float* __restrict__ b_ih,
        const float* __restrict__ w_hh, const float* __restrict__ b_hh,
        float* __restrict__ nh_out, float* __restrict__ nh_ws) {
    __shared__ float s_x[16 * 128];
    __shared__ float s_h[16 * 512];
    __shared__ float s_p[6 * 256];
    int bid = blockIdx.x;
    int tid = threadIdx.x;
    if (bid < 128) {
        int jb = bid;  // 0..127
        int j0 = jb * 4;
        for (int i = tid; i < 512; i += 256) ((float4*)s_x)[i] = ((const float4*)x)[i];
        for (int i = tid; i < 2048; i += 256) ((float4*)s_h)[i] = ((const float4*)hidden)[i];
        __syncthreads();
        int b = tid & 15, jl = (tid >> 4) & 3, q = tid >> 6;  // q 0..3
        int j = j0 + jl;
        float air = 0.f, aiz = 0.f, ain = 0.f, ahr = 0.f, ahz = 0.f, ahn = 0.f;
        {
            const float4* xi = (const float4*)(s_x + b * 128 + q * 32);
            const float4* w0 = (const float4*)(w_ih + (size_t)j * IN_F + q * 32);
            const float4* w1 = (const float4*)(w_ih + (size_t)(HH + j) * IN_F + q * 32);
            const float4* w2 = (const float4*)(w_ih + (size_t)(2 * HH + j) * IN_F + q * 32);
#pragma unroll
            for (int i = 0; i < 8; ++i) {
                float4 xv = xi[i];
                float4 a = w0[i], c = w1[i], d = w2[i];
                air += xv.x * a.x + xv.y * a.y + xv.z * a.z + xv.w * a.w;
                aiz += xv.x * c.x + xv.y * c.y + xv.z * c.z + xv.w * c.w;
                ain += xv.x * d.x + xv.y * d.y + xv.z * d.z + xv.w * d.w;
            }
        }
        {
            const float4* hi = (const float4*)(s_h + b * 512 + q * 128);
            const float4* w0 = (const float4*)(w_hh + (size_t)j * HH + q * 128);
            const float4* w1 = (const float4*)(w_hh + (size_t)(HH + j) * HH + q * 128);
            const float4* w2 = (const float4*)(w_hh + (size_t)(2 * HH + j) * HH + q * 128);
#pragma unroll 8
            for (int i = 0; i < 32; ++i) {
                float4 hv = hi[i];
                float4 a = w0[i], c = w1[i], d = w2[i];
                ahr += hv.x * a.x + hv.y * a.y + hv.z * a.z + hv.w * a.w;
                ahz += hv.x * c.x + hv.y * c.y + hv.z * c.z + hv.w * c.w;
                ahn += hv.x * d.x + hv.y * d.y + hv.z * d.z + hv.w * d.w;
            }
        }
        int pi = q * 64 + jl * 16 + b;
        s_p[0 * 256 + pi] = air; s_p[1 * 256 + pi] = aiz; s_p[2 * 256 + pi] = ain;
        s_p[3 * 256 + pi] = ahr; s_p[4 * 256 + pi] = ahz; s_p[5 * 256 + pi] = ahn;
        __syncthreads();
        if (tid < 64) {
            int b2 = tid & 15, jl2 = tid >> 4;
            int jj = j0 + jl2;
            float v0 = 0.f, v1 = 0.f, v2 = 0.f, v3 = 0.f, v4 = 0.f, v5 = 0.f;
#pragma unroll
            for (int qq = 0; qq < 4; ++qq) {
                int idx = qq * 64 + jl2 * 16 + b2;
                v0 += s_p[0 * 256 + idx]; v1 += s_p[1 * 256 + idx]; v2 += s_p[2 * 256 + idx];
                v3 += s_p[3 * 256 + idx]; v4 += s_p[4 * 256 + idx]; v5 += s_p[5 * 256 + idx];
            }
            float ir = v0 + b_ih[jj], iz = v1 + b_ih[HH + jj], inn = v2 + b_ih[2 * HH + jj];
            float hr = v3 + b_hh[jj], hz = v4 + b_hh[HH + jj], hn = v5 + b_hh[2 * HH + jj];
            float r = 1.f / (1.f + expf(-(ir + hr)));
            float z = 1.f / (1.f + expf(-(iz + hz)));
            float nn = tanhf(inn + r * hn);
            float hprev = s_h[b2 * 512 + jj];
            float nh = (1.f - z) * nn + z * hprev;
            nh_out[b2 * HH + jj] = nh;
            nh_ws[b2 * HH + jj] = nh;
        }
        return;
    }
    if (bid < 1152) {
        csr2[(bid - 128) * 256 + tid] = NN;  // sentinel -> zero feature block
        return;
    }
    if (bid < 1169) {
        cursor[(bid - 1152) * 256 + tid] = 0;  // 4352 ints incl sentinel slot
        return;
    }
    if (bid == 1169) {
        float* sm3 = s_p;  // reuse smem, 192 floats
        if (tid < 192) {
            int f = tid / 3, c = tid - 3 * (tid / 3);
            float acc = 0.f;
            for (int g = 0; g < 64; ++g) acc += W1[f * 64 + g] * w_out[(8 + g) * 3 + c];
            sm3[tid] = acc;
        }
        __syncthreads();
        if (tid < 9) {
            int k = tid / 3, c = tid - 3 * (tid / 3);
            float acc = 0.f;
            for (int f = 0; f < 64; ++f) acc += W0[k * 64 + f] * sm3[f * 3 + c];
            sm[tid] = acc;
        } else if (tid < 12) {
            int c = tid - 9;
            float acc = 0.f;
            for (int f = 0; f < 64; ++f) acc += b0[f] * sm3[f * 3 + c];
            sm[tid] = acc;
        } else if (tid < 15) {
            int c = tid - 12;
            float acc = 0.f;
            for (int g = 0; g < 64; ++g) acc += b1[g] * w_out[(8 + g) * 3 + c];
            sm[tid] = acc;
        }
        return;
    }
    int vb = bid - 1170;  // 0..1024
    int n = vb * 4 + (tid >> 6);
    int l = tid & 63;
    if (n > NN) return;
    if (n == NN) { pv[(size_t)NN * 64 + l] = 0.f; return; }
    int b = l >> 2, c = l & 3;
    float val = (c < 3) ? pos[(size_t)b * (NN * 3) + n * 3 + c] : 0.f;
    pv[(size_t)n * 64 + l] = val;
}

// ---------------- stage B: direct CSR fill (0..255)  ||  MLP1 (256..383) ----------------

__global__ void k_stageB(const int* __restrict__ src, const int* __restrict__ dst,
                         int* __restrict__ cursor, int* __restrict__ csr2,
                         const float* __restrict__ nh, const float* __restrict__ w1,
                         const float* __restrict__ b1v, const float* __restrict__ alpha1,
                         const float* __restrict__ g1, const float* __restrict__ bt1,
                         const float* __restrict__ mu1, const float* __restrict__ var1,
                         float* __restrict__ m1) {
    __shared__ float s_nh[512];
    __shared__ float s_p[4 * 64];
    int bid = blockIdx.x;
    int tid = threadIdx.x;
    if (bid < 256) {
        int i = bid * 256 + tid;
        int d = dst[i];
        int slot = atomicAdd(&cursor[d], 1);
        if (slot < CAP) csr2[d * CAP + slot] = src[i];
        return;
    }
    int mb = bid - 256;  // 0..127
    int b = mb >> 3;
    int jblk = mb & 7;
    for (int i = tid; i < 512; i += 256) s_nh[i] = nh[b * HH + i];
    __syncthreads();
    int jloc = tid & 63;
    int ks = tid >> 6;
    int j = jblk * 64 + jloc;
    const float* wp = w1 + (size_t)(ks * 128) * D1 + j;
    float acc = 0.f;
#pragma unroll 4
    for (int k0 = 0; k0 < 128; k0 += 4) {
        float w0 = wp[0], w1v = wp[D1], w2v = wp[2 * D1], w3v = wp[3 * D1];
        float4 mv = *(const float4*)&s_nh[ks * 128 + k0];
        acc += mv.x * w0 + mv.y * w1v + mv.z * w2v + mv.w * w3v;
        wp += 4 * D1;
    }
    s_p[ks * 64 + jloc] = acc;
    __syncthreads();
    if (tid < 64) {
        int jj = jblk * 64 + tid;
        float v = s_p[tid] + s_p[64 + tid] + s_p[128 + tid] + s_p[192 + tid];
        v += b1v[jj];
        float al = alpha1[jj];
        v = v > 0.f ? v : al * v;
        float iv = rsqrtf(var1[jj] + EPSV);
        m1[b * D1 + jj] = g1[jj] * (v - mu1[jj]) * iv + bt1[jj];
    }
}

// ---------------- mlp2 unit: 4 K-slices of 128; 4-deep w2 register prefetch; coalesced writes ----------------
// part[(ok*16+b)*D2 + j], ok in 0..3 -> 8 MB total

__device__ __forceinline__ void mlp2_unit(int jt, int ok, const float* __restrict__ m1,
                                          const float* __restrict__ w2,
                                          float* __restrict__ part,
                                          float* s_m1, int tid) {
    {
        int b = tid >> 4, kg = tid & 15;
        const float4* sp = (const float4*)(m1 + b * 512 + ok * 128 + kg * 8);
        float4* dp = (float4*)&s_m1[b * 128 + kg * 8];
        dp[0] = sp[0];
        dp[1] = sp[1];
    }
    __syncthreads();
    int j = jt * 512 + tid * 2;
    const float* wp = w2 + (size_t)(ok * 128) * D2 + j;
    float2 wb0 = *(const float2*)(wp + 0 * (size_t)D2);
    float2 wb1 = *(const float2*)(wp + 1 * (size_t)D2);
    float2 wb2 = *(const float2*)(wp + 2 * (size_t)D2);
    float2 wb3 = *(const float2*)(wp + 3 * (size_t)D2);
    float acc0[16], acc1[16];
#pragma unroll
    for (int b = 0; b < 16; ++b) { acc0[b] = 0.f; acc1[b] = 0.f; }
    for (int k4 = 0; k4 < 128; k4 += 4) {
        float2 c0 = wb0, c1 = wb1, c2 = wb2, c3 = wb3;
        int kp = (k4 + 4 < 128) ? k4 + 4 : 0;
        wb0 = *(const float2*)(wp + (size_t)(kp + 0) * D2);
        wb1 = *(const float2*)(wp + (size_t)(kp + 1) * D2);
        wb2 = *(const float2*)(wp + (size_t)(kp + 2) * D2);
        wb3 = *(const float2*)(wp + (size_t)(kp + 3) * D2);
#pragma unroll
        for (int b = 0; b < 16; ++b) {
            float2 p01 = *(const float2*)&s_m1[b * 128 + k4];
            float2 p23 = *(const float2*)&s_m1[b * 128 + k4 + 2];
            acc0[b] += p01.x * c0.x + p01.y * c1.x + p23.x * c2.x + p23.y * c3.x;
            acc1[b] += p01.x * c0.y + p01.y * c1.y + p23.x * c2.y + p23.y * c3.y;
        }
    }
    float* pb = part + (size_t)(ok * 16) * D2 + j;
#pragma unroll
    for (int b = 0; b < 16; ++b) {
        *(float2*)(pb + (size_t)b * D2) = make_float2(acc0[b], acc1[b]);
    }
}

// ---------------- stage C: FULL MLP2 ok 0..3 (0..255) || gather pass 1 w/ per-edge dis (256..1280) ----------------

__global__ __launch_bounds__(256) void k_stageC(
        const float* __restrict__ m1, const float* __restrict__ w2,
        float* __restrict__ part, const float* __restrict__ pv,
        const int* __restrict__ cursor, const int* __restrict__ csr2,
        const float* __restrict__ sm, float* __restrict__ u) {
    __shared__ float smem[2048];
    __shared__ int sidx[4][CAP];
    __shared__ float sP[4][64];
    int bid = blockIdx.x;
    int tid = threadIdx.x;
    if (bid < 256) {
        mlp2_unit(bid >> 2, bid & 3, m1, w2, part, smem, tid);
        return;
    }
    int gb = bid - 256;  // 0..1024
    int w = tid >> 6;
    int l = tid & 63;
    int n = gb * 4 + w;
    if (n > NN) return;
    if (n == NN) { u[(size_t)NN * 64 + l] = 0.f; return; }
    const int* row = csr2 + n * CAP;
    sidx[w][l] = row[l];
    int degc = cursor[n];
    int deg = degc < CAP ? degc : CAP;
    float dn = rsqrtf((float)(degc + 1));
    float acc = dn * pv[(size_t)n * 64 + l];
    int nch = (deg + 7) >> 3;
    float A[8], B[8], cA[8], cB[8];
    if (nch > 0) {
#pragma unroll
        for (int i = 0; i < 8; ++i) {
            int s = sidx[w][i];
            A[i] = pv[(size_t)s * 64 + l];
            cA[i] = (float)cursor[s];
        }
    }
    for (int c = 0; c < nch; ++c) {
        if (c + 1 < nch) {
            int base = (c + 1) * 8;
#pragma unroll
            for (int i = 0; i < 8; ++i) {
                int s = sidx[w][base + i];
                B[i] = pv[(size_t)s * 64 + l];
                cB[i] = (float)cursor[s];
            }
        }
#pragma unroll
        for (int i = 0; i < 8; ++i) acc += rsqrtf(cA[i] + 1.f) * A[i];
        if (c + 1 < nch) {
#pragma unroll
            for (int i = 0; i < 8; ++i) { A[i] = B[i]; cA[i] = cB[i]; }
        }
    }
    sP[w][l] = acc;
    int base = l & ~3;
    float P0 = sP[w][base + 0], P1 = sP[w][base + 1], P2 = sP[w][base + 2];
    int c = l & 3;
    float uu = 0.f;
    if (c < 3)
        uu = dn * dn * (P0 * sm[c] + P1 * sm[3 + c] + P2 * sm[6 + c]) + dn * sm[9 + c];
    u[(size_t)n * 64 + l] = uu;
}

// ---------------- stage D: gather pass 2 + fused output head (shuffle ok-reduction over 4) ----------------

__global__ __launch_bounds__(256) void k_stageD(
        const float* __restrict__ u, const int* __restrict__ cursor,
        const int* __restrict__ csr2, const float* __restrict__ sm,
        const float* __restrict__ part,
        const float* __restrict__ b2, const float* __restrict__ alpha2,
        const float* __restrict__ g2, const float* __restrict__ bt2,
        const float* __restrict__ mu2, const float* __restrict__ var2,
        const float* __restrict__ w_out, const float* __restrict__ b_out,
        float* __restrict__ y) {
    __shared__ int sidx[4][CAP];
    __shared__ float sV[4][128];
    int w = threadIdx.x >> 6;
    int l = threadIdx.x & 63;
    int n = blockIdx.x * 4 + w;  // grid 1024 -> n < 4096
    const int* row = csr2 + n * CAP;
    sidx[w][l] = row[l];
    // issue part read early: row l (= ok*16+b, ok=l>>4, b=l&15) of this node's slice
    const float4* pr0 = (const float4*)(part + (size_t)l * D2 + n * 8);
    float4 ra0 = pr0[0], ra1 = pr0[1];
    int degc = cursor[n];
    int deg = degc < CAP ? degc : CAP;
    float acc = u[(size_t)n * 64 + l];
    int nch = (deg + 7) >> 3;
    float A[8], B[8];
    if (nch > 0) {
#pragma unroll
        for (int i = 0; i < 8; ++i) A[i] = u[(size_t)sidx[w][i] * 64 + l];
    }
    for (int c = 0; c < nch; ++c) {
        if (c + 1 < nch) {
            int base = (c + 1) * 8;
#pragma unroll
            for (int i = 0; i < 8; ++i) B[i] = u[(size_t)sidx[w][base + i] * 64 + l];
        }
#pragma unroll
        for (int i = 0; i < 8; ++i) acc += A[i];
        if (c + 1 < nch) {
#pragma unroll
            for (int i = 0; i < 8; ++i) A[i] = B[i];
        }
    }
    float d = rsqrtf((float)(degc + 1));
    float hval = d * acc + (((l & 3) < 3) ? sm[12 + (l & 3)] : 0.f);
    // ok-reduction via shuffles: lanes {l, l^16, l^32, l^48} hold ok 0..3 for b=l&15
    float vg[8] = {ra0.x, ra0.y, ra0.z, ra0.w, ra1.x, ra1.y, ra1.z, ra1.w};
#pragma unroll
    for (int g = 0; g < 8; ++g) vg[g] += __shfl_xor(vg[g], 16);
#pragma unroll
    for (int g = 0; g < 8; ++g) vg[g] += __shfl_xor(vg[g], 32);
    // lanes 0..15 hold full sums for b = l; apply bias/PReLU/BN, stage in sV
    if (l < 16) {
#pragma unroll
        for (int g = 0; g < 8; ++g) {
            int j = n * 8 + g;
            float v = vg[g] + b2[j];
            float al = alpha2[j];
            v = v > 0.f ? v : al * v;
            v = g2[j] * (v - mu2[j]) * rsqrtf(var2[j] + EPSV) + bt2[j];
            sV[w][g * 16 + l] = v;
        }
    }
    __syncthreads();
    int bb = l >> 2, c = l & 3;
    if (c < 3) {
        float y0 = b_out[c] + hval;
#pragma unroll
        for (int g = 0; g < 8; ++g) y0 += sV[w][g * 16 + bb] * w_out[g * 3 + c];
        y[(size_t)bb * (NN * 3) + n * 3 + c] = y0;
    }
}

// ---------------- launcher ----------------

extern "C" void kernel_launch(void* const* d_in, const int* in_sizes, int n_in,
                              void* d_out, int out_size, void* d_ws, size_t ws_size,
                              hipStream_t stream) {
    const float* x      = (const float*)d_in[0];
    const float* pos    = (const float*)d_in[1];
    const float* hidden = (const float*)d_in[2];
    const int*   ei     = (const int*)d_in[3];
    const float* W0     = (const float*)d_in[4];
    const float* b0     = (const float*)d_in[5];
    const float* W1     = (const float*)d_in[6];
    const float* b1     = (const float*)d_in[7];
    const float* w_ih   = (const float*)d_in[8];
    const float* b_ih   = (const float*)d_in[9];
    const float* w_hh   = (const float*)d_in[10];
    const float* b_hh   = (const float*)d_in[11];
    const float* mlp_w1 = (const float*)d_in[12];
    const float* mlp_b1 = (const float*)d_in[13];
    const float* alpha1 = (const float*)d_in[14];
    const float* bn1g   = (const float*)d_in[15];
    const float* bn1b   = (const float*)d_in[16];
    const float* bn1m   = (const float*)d_in[17];
    const float* bn1v   = (const float*)d_in[18];
    const float* mlp_w2 = (const float*)d_in[19];
    const float* mlp_b2 = (const float*)d_in[20];
    const float* alpha2 = (const float*)d_in[21];
    const float* bn2g   = (const float*)d_in[22];
    const float* bn2b   = (const float*)d_in[23];
    const float* bn2m   = (const float*)d_in[24];
    const float* bn2v   = (const float*)d_in[25];
    const float* w_out  = (const float*)d_in[26];
    const float* b_out  = (const float*)d_in[27];

    float* out = (float*)d_out;
    float* ws = (float*)d_ws;

    // workspace layout (float offsets)
    float* pv   = ws;                  // 4097*64 = 262208
    float* u    = ws + 262208;         // 262208
    float* part = ws + 524416;         // 64*32768 = 2097152
    float* nh   = ws + 2621568;        // 8192
    float* m1   = ws + 2629760;        // 8192
    float* sm   = ws + 2637952;        // 16
    int* wsi    = (int*)(ws + 2637968);
    int* cursor = wsi;                 // 4352 (incl sentinel slot 4096, stays 0)
    int* csr2   = wsi + 4352;          // 4096*64 = 262144

    const int* srcp = ei;
    const int* dstp = ei + EE;

    k_stageA<<<128 + 1024 + 17 + 1 + 1025, 256, 0, stream>>>(
        csr2, cursor, W0, b0, W1, b1, w_out, sm, pos, pv, x, hidden, w_ih, b_ih, w_hh,
        b_hh, out + BB * NN * 3, nh);
    k_stageB<<<256 + 128, 256, 0, stream>>>(srcp, dstp, cursor, csr2, nh, mlp_w1, mlp_b1,
                                            alpha1, bn1g, bn1b, bn1m, bn1v, m1);
    k_stageC<<<256 + 1025, 256, 0, stream>>>(m1, mlp_w2, part, pv, cursor, csr2, sm, u);
    k_stageD<<<1024, 256, 0, stream>>>(u, cursor, csr2, sm, part, mlp_b2, alpha2, bn2g,
                                       bn2b, bn2m, bn2v, w_out, b_out, out);
}

// Round 20
// 51.542 us; speedup vs baseline: 1.0688x; 1.0688x over previous
//
#include <hip/hip_runtime.h>
#include <math.h>

#define BB 16
#define NN 4096
#define EE 65536
#define IN_F 128
#define HH 512
#define D1 512
#define D2 32768
#define EPSV 1e-5f
#define CAP 64  // fixed CSR row capacity; dst ~ Binomial(65536,1/4096), P(deg>64)~1e-19

// ---------------- stage A: GRU (0..127) || csr2 sentinel (128..1151) || cursor zero (1152..1168)
//                  || sm precompute (1169) || pv build (1170..2194) ----------------
// pv[n][l] = raw pos (l = b*4+c, c<3); dis applied per-edge in gath1.
// sm layout: [0..8] W0M3 (3x3 row-major k*3+c), [9..11] b0@M3, [12..14] b1@Wh

__global__ __launch_bounds__(256) void k_stageA(
        int* __restrict__ csr2, int* __restrict__ cursor,
        const float* __restrict__ W0, const float* __restrict__ b0,
        const float* __restrict__ W1, const float* __restrict__ b1,
        const float* __restrict__ w_out, float* __restrict__ sm,
        const float* __restrict__ pos, float* __restrict__ pv,
        const float* __restrict__ x, const float* __restrict__ hidden,
        const float* __restrict__ w_ih, const float* __restrict__ b_ih,
        const float* __restrict__ w_hh, const float* __restrict__ b_hh,
        float* __restrict__ nh_out, float* __restrict__ nh_ws) {
    __shared__ float s_x[16 * 128];
    __shared__ float s_h[16 * 512];
    __shared__ float s_p[6 * 256];
    int bid = blockIdx.x;
    int tid = threadIdx.x;
    if (bid < 128) {
        int jb = bid;  // 0..127
        int j0 = jb * 4;
        for (int i = tid; i < 512; i += 256) ((float4*)s_x)[i] = ((const float4*)x)[i];
        for (int i = tid; i < 2048; i += 256) ((float4*)s_h)[i] = ((const float4*)hidden)[i];
        __syncthreads();
        int b = tid & 15, jl = (tid >> 4) & 3, q = tid >> 6;  // q 0..3
        int j = j0 + jl;
        float air = 0.f, aiz = 0.f, ain = 0.f, ahr = 0.f, ahz = 0.f, ahn = 0.f;
        {
            const float4* xi = (const float4*)(s_x + b * 128 + q * 32);
            const float4* w0 = (const float4*)(w_ih + (size_t)j * IN_F + q * 32);
            const float4* w1 = (const float4*)(w_ih + (size_t)(HH + j) * IN_F + q * 32);
            const float4* w2 = (const float4*)(w_ih + (size_t)(2 * HH + j) * IN_F + q * 32);
#pragma unroll
            for (int i = 0; i < 8; ++i) {
                float4 xv = xi[i];
                float4 a = w0[i], c = w1[i], d = w2[i];
                air += xv.x * a.x + xv.y * a.y + xv.z * a.z + xv.w * a.w;
                aiz += xv.x * c.x + xv.y * c.y + xv.z * c.z + xv.w * c.w;
                ain += xv.x * d.x + xv.y * d.y + xv.z * d.z + xv.w * d.w;
            }
        }
        {
            const float4* hi = (const float4*)(s_h + b * 512 + q * 128);
            const float4* w0 = (const float4*)(w_hh + (size_t)j * HH + q * 128);
            const float4* w1 = (const float4*)(w_hh + (size_t)(HH + j) * HH + q * 128);
            const float4* w2 = (const float4*)(w_hh + (size_t)(2 * HH + j) * HH + q * 128);
#pragma unroll 8
            for (int i = 0; i < 32; ++i) {
                float4 hv = hi[i];
                float4 a = w0[i], c = w1[i], d = w2[i];
                ahr += hv.x * a.x + hv.y * a.y + hv.z * a.z + hv.w * a.w;
                ahz += hv.x * c.x + hv.y * c.y + hv.z * c.z + hv.w * c.w;
                ahn += hv.x * d.x + hv.y * d.y + hv.z * d.z + hv.w * d.w;
            }
        }
        int pi = q * 64 + jl * 16 + b;
        s_p[0 * 256 + pi] = air; s_p[1 * 256 + pi] = aiz; s_p[2 * 256 + pi] = ain;
        s_p[3 * 256 + pi] = ahr; s_p[4 * 256 + pi] = ahz; s_p[5 * 256 + pi] = ahn;
        __syncthreads();
        if (tid < 64) {
            int b2 = tid & 15, jl2 = tid >> 4;
            int jj = j0 + jl2;
            float v0 = 0.f, v1 = 0.f, v2 = 0.f, v3 = 0.f, v4 = 0.f, v5 = 0.f;
#pragma unroll
            for (int qq = 0; qq < 4; ++qq) {
                int idx = qq * 64 + jl2 * 16 + b2;
                v0 += s_p[0 * 256 + idx]; v1 += s_p[1 * 256 + idx]; v2 += s_p[2 * 256 + idx];
                v3 += s_p[3 * 256 + idx]; v4 += s_p[4 * 256 + idx]; v5 += s_p[5 * 256 + idx];
            }
            float ir = v0 + b_ih[jj], iz = v1 + b_ih[HH + jj], inn = v2 + b_ih[2 * HH + jj];
            float hr = v3 + b_hh[jj], hz = v4 + b_hh[HH + jj], hn = v5 + b_hh[2 * HH + jj];
            float r = 1.f / (1.f + expf(-(ir + hr)));
            float z = 1.f / (1.f + expf(-(iz + hz)));
            float nn = tanhf(inn + r * hn);
            float hprev = s_h[b2 * 512 + jj];
            float nh = (1.f - z) * nn + z * hprev;
            nh_out[b2 * HH + jj] = nh;
            nh_ws[b2 * HH + jj] = nh;
        }
        return;
    }
    if (bid < 1152) {
        csr2[(bid - 128) * 256 + tid] = NN;  // sentinel -> zero feature block
        return;
    }
    if (bid < 1169) {
        cursor[(bid - 1152) * 256 + tid] = 0;  // 4352 ints incl sentinel slot
        return;
    }
    if (bid == 1169) {
        float* sm3 = s_p;  // reuse smem, 192 floats
        if (tid < 192) {
            int f = tid / 3, c = tid - 3 * (tid / 3);
            float acc = 0.f;
            for (int g = 0; g < 64; ++g) acc += W1[f * 64 + g] * w_out[(8 + g) * 3 + c];
            sm3[tid] = acc;
        }
        __syncthreads();
        if (tid < 9) {
            int k = tid / 3, c = tid - 3 * (tid / 3);
            float acc = 0.f;
            for (int f = 0; f < 64; ++f) acc += W0[k * 64 + f] * sm3[f * 3 + c];
            sm[tid] = acc;
        } else if (tid < 12) {
            int c = tid - 9;
            float acc = 0.f;
            for (int f = 0; f < 64; ++f) acc += b0[f] * sm3[f * 3 + c];
            sm[tid] = acc;
        } else if (tid < 15) {
            int c = tid - 12;
            float acc = 0.f;
            for (int g = 0; g < 64; ++g) acc += b1[g] * w_out[(8 + g) * 3 + c];
            sm[tid] = acc;
        }
        return;
    }
    int vb = bid - 1170;  // 0..1024
    int n = vb * 4 + (tid >> 6);
    int l = tid & 63;
    if (n > NN) return;
    if (n == NN) { pv[(size_t)NN * 64 + l] = 0.f; return; }
    int b = l >> 2, c = l & 3;
    float val = (c < 3) ? pos[(size_t)b * (NN * 3) + n * 3 + c] : 0.f;
    pv[(size_t)n * 64 + l] = val;
}

// ---------------- stage B: direct CSR fill (0..255)  ||  MLP1 (256..383) ----------------

__global__ void k_stageB(const int* __restrict__ src, const int* __restrict__ dst,
                         int* __restrict__ cursor, int* __restrict__ csr2,
                         const float* __restrict__ nh, const float* __restrict__ w1,
                         const float* __restrict__ b1v, const float* __restrict__ alpha1,
                         const float* __restrict__ g1, const float* __restrict__ bt1,
                         const float* __restrict__ mu1, const float* __restrict__ var1,
                         float* __restrict__ m1) {
    __shared__ float s_nh[512];
    __shared__ float s_p[4 * 64];
    int bid = blockIdx.x;
    int tid = threadIdx.x;
    if (bid < 256) {
        int i = bid * 256 + tid;
        int d = dst[i];
        int slot = atomicAdd(&cursor[d], 1);
        if (slot < CAP) csr2[d * CAP + slot] = src[i];
        return;
    }
    int mb = bid - 256;  // 0..127
    int b = mb >> 3;
    int jblk = mb & 7;
    for (int i = tid; i < 512; i += 256) s_nh[i] = nh[b * HH + i];
    __syncthreads();
    int jloc = tid & 63;
    int ks = tid >> 6;
    int j = jblk * 64 + jloc;
    const float* wp = w1 + (size_t)(ks * 128) * D1 + j;
    float acc = 0.f;
#pragma unroll 4
    for (int k0 = 0; k0 < 128; k0 += 4) {
        float w0 = wp[0], w1v = wp[D1], w2v = wp[2 * D1], w3v = wp[3 * D1];
        float4 mv = *(const float4*)&s_nh[ks * 128 + k0];
        acc += mv.x * w0 + mv.y * w1v + mv.z * w2v + mv.w * w3v;
        wp += 4 * D1;
    }
    s_p[ks * 64 + jloc] = acc;
    __syncthreads();
    if (tid < 64) {
        int jj = jblk * 64 + tid;
        float v = s_p[tid] + s_p[64 + tid] + s_p[128 + tid] + s_p[192 + tid];
        v += b1v[jj];
        float al = alpha1[jj];
        v = v > 0.f ? v : al * v;
        float iv = rsqrtf(var1[jj] + EPSV);
        m1[b * D1 + jj] = g1[jj] * (v - mu1[jj]) * iv + bt1[jj];
    }
}

// ---------------- mlp2 unit: 4-deep w2 register prefetch (R15-proven); coalesced writes ----------------

__device__ __forceinline__ void mlp2_unit(int jt, int ok, const float* __restrict__ m1,
                                          const float* __restrict__ w2,
                                          float* __restrict__ part,
                                          float* s_m1, int tid) {
    {
        int b = tid >> 4, kg = tid & 15;
        *(float4*)&s_m1[b * 64 + kg * 4] = *(const float4*)(m1 + b * 512 + ok * 64 + kg * 4);
    }
    __syncthreads();
    int j = jt * 512 + tid * 2;
    const float* wp = w2 + (size_t)(ok * 64) * D2 + j;
    float2 wb0 = *(const float2*)(wp + 0 * (size_t)D2);
    float2 wb1 = *(const float2*)(wp + 1 * (size_t)D2);
    float2 wb2 = *(const float2*)(wp + 2 * (size_t)D2);
    float2 wb3 = *(const float2*)(wp + 3 * (size_t)D2);
    float acc0[16], acc1[16];
#pragma unroll
    for (int b = 0; b < 16; ++b) { acc0[b] = 0.f; acc1[b] = 0.f; }
    for (int k4 = 0; k4 < 64; k4 += 4) {
        float2 c0 = wb0, c1 = wb1, c2 = wb2, c3 = wb3;
        int kp = (k4 + 4 < 64) ? k4 + 4 : 0;
        wb0 = *(const float2*)(wp + (size_t)(kp + 0) * D2);
        wb1 = *(const float2*)(wp + (size_t)(kp + 1) * D2);
        wb2 = *(const float2*)(wp + (size_t)(kp + 2) * D2);
        wb3 = *(const float2*)(wp + (size_t)(kp + 3) * D2);
#pragma unroll
        for (int b = 0; b < 16; ++b) {
            float2 p01 = *(const float2*)&s_m1[b * 64 + k4];
            float2 p23 = *(const float2*)&s_m1[b * 64 + k4 + 2];
            acc0[b] += p01.x * c0.x + p01.y * c1.x + p23.x * c2.x + p23.y * c3.x;
            acc1[b] += p01.x * c0.y + p01.y * c1.y + p23.x * c2.y + p23.y * c3.y;
        }
    }
    float* pb = part + (size_t)(ok * 16) * D2 + j;
#pragma unroll
    for (int b = 0; b < 16; ++b) {
        *(float2*)(pb + (size_t)b * D2) = make_float2(acc0[b], acc1[b]);
    }
}

// ---------------- stage C: FULL MLP2 ok 0..7 (0..511) || gather pass 1 w/ per-edge dis (512..1536) ----------------

__global__ __launch_bounds__(256) void k_stageC(
        const float* __restrict__ m1, const float* __restrict__ w2,
        float* __restrict__ part, const float* __restrict__ pv,
        const int* __restrict__ cursor, const int* __restrict__ csr2,
        const float* __restrict__ sm, float* __restrict__ u) {
    __shared__ float smem[1024];
    __shared__ int sidx[4][CAP];
    __shared__ float sP[4][64];
    int bid = blockIdx.x;
    int tid = threadIdx.x;
    if (bid < 512) {
        mlp2_unit(bid >> 3, bid & 7, m1, w2, part, smem, tid);
        return;
    }
    int gb = bid - 512;  // 0..1024
    int w = tid >> 6;
    int l = tid & 63;
    int n = gb * 4 + w;
    if (n > NN) return;
    if (n == NN) { u[(size_t)NN * 64 + l] = 0.f; return; }
    const int* row = csr2 + n * CAP;
    sidx[w][l] = row[l];
    int degc = cursor[n];
    int deg = degc < CAP ? degc : CAP;
    float dn = rsqrtf((float)(degc + 1));
    float acc = dn * pv[(size_t)n * 64 + l];
    int nch = (deg + 7) >> 3;
    float A[8], B[8], cA[8], cB[8];
    if (nch > 0) {
#pragma unroll
        for (int i = 0; i < 8; ++i) {
            int s = sidx[w][i];
            A[i] = pv[(size_t)s * 64 + l];
            cA[i] = (float)cursor[s];
        }
    }
    for (int c = 0; c < nch; ++c) {
        if (c + 1 < nch) {
            int base = (c + 1) * 8;
#pragma unroll
            for (int i = 0; i < 8; ++i) {
                int s = sidx[w][base + i];
                B[i] = pv[(size_t)s * 64 + l];
                cB[i] = (float)cursor[s];
            }
        }
#pragma unroll
        for (int i = 0; i < 8; ++i) acc += rsqrtf(cA[i] + 1.f) * A[i];
        if (c + 1 < nch) {
#pragma unroll
            for (int i = 0; i < 8; ++i) { A[i] = B[i]; cA[i] = cB[i]; }
        }
    }
    sP[w][l] = acc;
    int base = l & ~3;
    float P0 = sP[w][base + 0], P1 = sP[w][base + 1], P2 = sP[w][base + 2];
    int c = l & 3;
    float uu = 0.f;
    if (c < 3)
        uu = dn * dn * (P0 * sm[c] + P1 * sm[3 + c] + P2 * sm[6 + c]) + dn * sm[9 + c];
    u[(size_t)n * 64 + l] = uu;
}

// ---------------- stage D: gather pass 2 + fused output head (shuffle ok-reduction) ----------------

__global__ __launch_bounds__(256) void k_stageD(
        const float* __restrict__ u, const int* __restrict__ cursor,
        const int* __restrict__ csr2, const float* __restrict__ sm,
        const float* __restrict__ part,
        const float* __restrict__ b2, const float* __restrict__ alpha2,
        const float* __restrict__ g2, const float* __restrict__ bt2,
        const float* __restrict__ mu2, const float* __restrict__ var2,
        const float* __restrict__ w_out, const float* __restrict__ b_out,
        float* __restrict__ y) {
    __shared__ int sidx[4][CAP];
    __shared__ float sV[4][128];
    int w = threadIdx.x >> 6;
    int l = threadIdx.x & 63;
    int n = blockIdx.x * 4 + w;  // grid 1024 -> n < 4096
    const int* row = csr2 + n * CAP;
    sidx[w][l] = row[l];
    // issue part reads early: rows l and 64+l of this node's slice
    const float4* pr0 = (const float4*)(part + (size_t)l * D2 + n * 8);
    const float4* pr1 = (const float4*)(part + (size_t)(64 + l) * D2 + n * 8);
    float4 ra0 = pr0[0], ra1 = pr0[1];
    float4 rb0 = pr1[0], rb1 = pr1[1];
    int degc = cursor[n];
    int deg = degc < CAP ? degc : CAP;
    float acc = u[(size_t)n * 64 + l];
    int nch = (deg + 7) >> 3;
    float A[8], B[8];
    if (nch > 0) {
#pragma unroll
        for (int i = 0; i < 8; ++i) A[i] = u[(size_t)sidx[w][i] * 64 + l];
    }
    for (int c = 0; c < nch; ++c) {
        if (c + 1 < nch) {
            int base = (c + 1) * 8;
#pragma unroll
            for (int i = 0; i < 8; ++i) B[i] = u[(size_t)sidx[w][base + i] * 64 + l];
        }
#pragma unroll
        for (int i = 0; i < 8; ++i) acc += A[i];
        if (c + 1 < nch) {
#pragma unroll
            for (int i = 0; i < 8; ++i) A[i] = B[i];
        }
    }
    float d = rsqrtf((float)(degc + 1));
    float hval = d * acc + (((l & 3) < 3) ? sm[12 + (l & 3)] : 0.f);
    // ok-reduction via shuffles: lane l holds rows (ok=l>>4, b=l&15) and (ok+4, b)
    float vg[8] = {ra0.x + rb0.x, ra0.y + rb0.y, ra0.z + rb0.z, ra0.w + rb0.w,
                   ra1.x + rb1.x, ra1.y + rb1.y, ra1.z + rb1.z, ra1.w + rb1.w};
#pragma unroll
    for (int g = 0; g < 8; ++g) vg[g] += __shfl_xor(vg[g], 16);
#pragma unroll
    for (int g = 0; g < 8; ++g) vg[g] += __shfl_xor(vg[g], 32);
    // lanes 0..15 hold full sums for b = l; apply bias/PReLU/BN, stage in sV
    if (l < 16) {
#pragma unroll
        for (int g = 0; g < 8; ++g) {
            int j = n * 8 + g;
            float v = vg[g] + b2[j];
            float al = alpha2[j];
            v = v > 0.f ? v : al * v;
            v = g2[j] * (v - mu2[j]) * rsqrtf(var2[j] + EPSV) + bt2[j];
            sV[w][g * 16 + l] = v;
        }
    }
    __syncthreads();
    int bb = l >> 2, c = l & 3;
    if (c < 3) {
        float y0 = b_out[c] + hval;
#pragma unroll
        for (int g = 0; g < 8; ++g) y0 += sV[w][g * 16 + bb] * w_out[g * 3 + c];
        y[(size_t)bb * (NN * 3) + n * 3 + c] = y0;
    }
}

// ---------------- launcher ----------------

extern "C" void kernel_launch(void* const* d_in, const int* in_sizes, int n_in,
                              void* d_out, int out_size, void* d_ws, size_t ws_size,
                              hipStream_t stream) {
    const float* x      = (const float*)d_in[0];
    const float* pos    = (const float*)d_in[1];
    const float* hidden = (const float*)d_in[2];
    const int*   ei     = (const int*)d_in[3];
    const float* W0     = (const float*)d_in[4];
    const float* b0     = (const float*)d_in[5];
    const float* W1     = (const float*)d_in[6];
    const float* b1     = (const float*)d_in[7];
    const float* w_ih   = (const float*)d_in[8];
    const float* b_ih   = (const float*)d_in[9];
    const float* w_hh   = (const float*)d_in[10];
    const float* b_hh   = (const float*)d_in[11];
    const float* mlp_w1 = (const float*)d_in[12];
    const float* mlp_b1 = (const float*)d_in[13];
    const float* alpha1 = (const float*)d_in[14];
    const float* bn1g   = (const float*)d_in[15];
    const float* bn1b   = (const float*)d_in[16];
    const float* bn1m   = (const float*)d_in[17];
    const float* bn1v   = (const float*)d_in[18];
    const float* mlp_w2 = (const float*)d_in[19];
    const float* mlp_b2 = (const float*)d_in[20];
    const float* alpha2 = (const float*)d_in[21];
    const float* bn2g   = (const float*)d_in[22];
    const float* bn2b   = (const float*)d_in[23];
    const float* bn2m   = (const float*)d_in[24];
    const float* bn2v   = (const float*)d_in[25];
    const float* w_out  = (const float*)d_in[26];
    const float* b_out  = (const float*)d_in[27];

    float* out = (float*)d_out;
    float* ws = (float*)d_ws;

    // workspace layout (float offsets)
    float* pv   = ws;                  // 4097*64 = 262208
    float* u    = ws + 262208;         // 262208
    float* part = ws + 524416;         // 128*32768 = 4194304
    float* nh   = ws + 4718720;        // 8192
    float* m1   = ws + 4726912;        // 8192
    float* sm   = ws + 4735104;        // 16
    int* wsi    = (int*)(ws + 4735120);
    int* cursor = wsi;                 // 4352 (incl sentinel slot 4096, stays 0)
    int* csr2   = wsi + 4352;          // 4096*64 = 262144

    const int* srcp = ei;
    const int* dstp = ei + EE;

    k_stageA<<<128 + 1024 + 17 + 1 + 1025, 256, 0, stream>>>(
        csr2, cursor, W0, b0, W1, b1, w_out, sm, pos, pv, x, hidden, w_ih, b_ih, w_hh,
        b_hh, out + BB * NN * 3, nh);
    k_stageB<<<256 + 128, 256, 0, stream>>>(srcp, dstp, cursor, csr2, nh, mlp_w1, mlp_b1,
                                            alpha1, bn1g, bn1b, bn1m, bn1v, m1);
    k_stageC<<<512 + 1025, 256, 0, stream>>>(m1, mlp_w2, part, pv, cursor, csr2, sm, u);
    k_stageD<<<1024, 256, 0, stream>>>(u, cursor, csr2, sm, part, mlp_b2, alpha2, bn2g,
                                       bn2b, bn2m, bn2v, w_out, b_out, out);
}